// Round 7
// baseline (388.874 us; speedup 1.0000x reference)
//
#include <hip/hip_runtime.h>
#include <hip/hip_bf16.h>

// Problem constants
#define DD 2048
#define SS 10240
#define KK 4096   // 2*DD

typedef __bf16 bf16x8 __attribute__((ext_vector_type(8)));
typedef float  f32x4  __attribute__((ext_vector_type(4)));

__device__ __forceinline__ unsigned short f2bf_rne(float x) {
    unsigned int u = __float_as_uint(x);
    u += 0x7FFFu + ((u >> 16) & 1u);
    return (unsigned short)(u >> 16);
}

// ---------------------------------------------------------------------------
// Fused prep+sim (one launch):
//  blocks [0,2048):      W1 [4096][2048] f32 -> W1T [2048][4096] bf16,
//                        plus s_pre init = b2
//  blocks [2048,12288):  sim row s = blockIdx-2048: bf16 [SS][KK]
// ---------------------------------------------------------------------------
__global__ __launch_bounds__(256) void prep_sim_kernel(
    const float* __restrict__ W1, const float* __restrict__ b2,
    const float* __restrict__ x0, const float* __restrict__ x1,
    unsigned short* __restrict__ W1T, float* __restrict__ s_pre,
    unsigned short* __restrict__ simB) {
    __shared__ float tile[64][65];
    const int t = threadIdx.x;

    if (blockIdx.x < (KK / 64) * (DD / 64)) {
        const int bf = blockIdx.x % (KK / 64);
        const int bd = blockIdx.x / (KK / 64);
        const int f0 = bf * 64, d0 = bd * 64;
#pragma unroll
        for (int p = 0; p < 4; ++p) {
            int fr = p * 16 + (t >> 4);
            int dc = (t & 15) * 4;
            const float4 v = *(const float4*)&W1[(size_t)(f0 + fr) * DD + d0 + dc];
            tile[fr][dc + 0] = v.x; tile[fr][dc + 1] = v.y;
            tile[fr][dc + 2] = v.z; tile[fr][dc + 3] = v.w;
        }
        __syncthreads();
#pragma unroll
        for (int p = 0; p < 4; ++p) {
            int dr = p * 16 + (t >> 4);
            int fc = (t & 15) * 4;
            ushort4 o;
            o.x = f2bf_rne(tile[fc + 0][dr]);
            o.y = f2bf_rne(tile[fc + 1][dr]);
            o.z = f2bf_rne(tile[fc + 2][dr]);
            o.w = f2bf_rne(tile[fc + 3][dr]);
            *(ushort4*)&W1T[(size_t)(d0 + dr) * KK + f0 + fc] = o;
        }
        int gid = blockIdx.x * 256 + t;
        if (gid < SS) s_pre[gid] = b2[0];
    } else {
        const int s = blockIdx.x - (KK / 64) * (DD / 64);
        const int d = t * 8;
        const float4 a0 = *(const float4*)&x0[d];
        const float4 a1 = *(const float4*)&x0[d + 4];
        const float4 v0 = *(const float4*)&x1[(size_t)s * DD + d];
        const float4 v1 = *(const float4*)&x1[(size_t)s * DD + d + 4];
        ushort4 lo0, lo1, hi0, hi1;
        lo0.x = f2bf_rne(fabsf(a0.x - v0.x)); hi0.x = f2bf_rne(a0.x + v0.x);
        lo0.y = f2bf_rne(fabsf(a0.y - v0.y)); hi0.y = f2bf_rne(a0.y + v0.y);
        lo0.z = f2bf_rne(fabsf(a0.z - v0.z)); hi0.z = f2bf_rne(a0.z + v0.z);
        lo0.w = f2bf_rne(fabsf(a0.w - v0.w)); hi0.w = f2bf_rne(a0.w + v0.w);
        lo1.x = f2bf_rne(fabsf(a1.x - v1.x)); hi1.x = f2bf_rne(a1.x + v1.x);
        lo1.y = f2bf_rne(fabsf(a1.y - v1.y)); hi1.y = f2bf_rne(a1.y + v1.y);
        lo1.z = f2bf_rne(fabsf(a1.z - v1.z)); hi1.z = f2bf_rne(a1.z + v1.z);
        lo1.w = f2bf_rne(fabsf(a1.w - v1.w)); hi1.w = f2bf_rne(a1.w + v1.w);
        unsigned short* row = &simB[(size_t)s * KK];
        *(ushort4*)&row[d]          = lo0;
        *(ushort4*)&row[d + 4]      = lo1;
        *(ushort4*)&row[DD + d]     = hi0;
        *(ushort4*)&row[DD + d + 4] = hi1;
    }
}

// ---------------------------------------------------------------------------
// gemm3: 320x256 tile, BK=32, 512 thr (8 waves 4x2, wave out 80x128).
// 4-buffer / 3-tile-deep counted-vmcnt pipeline: stage tile kt+3 while
// computing kt -> every in-loop wait has ~3 BODYs of slack (staging latency
// fully hidden). 5 uniform gload_lds per wave per tile (round 5 duplicated
// across wave halves to keep PER-WAVE vmcnt counts uniform).
// Swizzle (BK=32): granule ^= (row>>1)&3, self-inverse, applied to global
// source AND ds_read (rule #21); exact 2-way bank access (free per m136).
// W-a-R safety: buffer (kt+3)&3 last read in BODY kt-1; stage issues after
// BODY kt's entry vmcnt->barrier (all reads consumed by MFMAs before it).
// R-a-W safety: per-wave vmcnt(10) confirms own tile-kt loads done, THEN
// barrier -> collectively tile kt fully landed before any ds_read.
// grid 256 = 1/CU; XCD pinning bm = i&31 (A-panel per XCD).
// ---------------------------------------------------------------------------
#define BM3 320
#define BN3 256
#define BK3 32
#define NKT (KK / BK3)   // 128
#define BUFSZ 18432      // ushorts per buffer: A 10240 + B 8192
#define BBASE 10240

// 5 gload_lds rounds per tile (per-thread gsrc[]/ldsoff[] precomputed)
#define STAGE(ktv)                                                             \
    {                                                                          \
        unsigned short* lbw = &lds[(ktv) & 3][0];                              \
        _Pragma("unroll")                                                      \
        for (int L = 0; L < 5; ++L)                                            \
            __builtin_amdgcn_global_load_lds(                                  \
                (const __attribute__((address_space(1))) void*)(gsrc[L] + (size_t)(ktv) * BK3), \
                (__attribute__((address_space(3))) void*)(lbw + ldsoff[L]),    \
                16, 0, 0);                                                     \
    }

#define BODY(ktv, VM_LIT, DO_STAGE)                                            \
    {                                                                          \
        asm volatile("s_waitcnt vmcnt(" VM_LIT ")" ::: "memory");              \
        __builtin_amdgcn_s_barrier();                                          \
        __builtin_amdgcn_sched_barrier(0);                                     \
        if (DO_STAGE) { STAGE((ktv) + 3) }                                     \
        const unsigned short* lbr = &lds[(ktv) & 3][0];                        \
        bf16x8 afr[5], bfr[4];                                                 \
        _Pragma("unroll")                                                      \
        for (int m = 0; m < 5; ++m)                                            \
            afr[m] = *(const bf16x8*)&lbr[aoff + m * 512];                     \
        _Pragma("unroll")                                                      \
        for (int n = 0; n < 4; ++n)                                            \
            bfr[n] = *(const bf16x8*)&lbr[boff + n * 512];                     \
        __builtin_amdgcn_s_barrier();                                          \
        __builtin_amdgcn_s_setprio(1);                                         \
        _Pragma("unroll")                                                      \
        for (int m = 0; m < 5; ++m)                                            \
            _Pragma("unroll")                                                  \
            for (int n = 0; n < 4; ++n)                                        \
                acc[m][n] = __builtin_amdgcn_mfma_f32_16x16x32_bf16(           \
                    afr[m], bfr[n], acc[m][n], 0, 0, 0);                       \
        __builtin_amdgcn_s_setprio(0);                                         \
        _Pragma("unroll")                                                      \
        for (int n = 0; n < 4; ++n)                                            \
            bfr[n] = *(const bf16x8*)&lbr[boff + (4 + n) * 512];               \
        __builtin_amdgcn_s_barrier();                                          \
        __builtin_amdgcn_s_setprio(1);                                         \
        _Pragma("unroll")                                                      \
        for (int m = 0; m < 5; ++m)                                            \
            _Pragma("unroll")                                                  \
            for (int n = 0; n < 4; ++n)                                        \
                acc[m][4 + n] = __builtin_amdgcn_mfma_f32_16x16x32_bf16(       \
                    afr[m], bfr[n], acc[m][4 + n], 0, 0, 0);                   \
        __builtin_amdgcn_s_setprio(0);                                         \
    }

__global__ __launch_bounds__(512, 2) void gemm3_kernel(
    const unsigned short* __restrict__ simB,
    const unsigned short* __restrict__ W1T,
    const float* __restrict__ b1, const float* __restrict__ W2,
    float* __restrict__ s_pre) {
    // 4 buffers x (A 320x32 | B 256x32) = 4 x 36 KB = 144 KB
    __shared__ unsigned short lds[4][BUFSZ];

    const int t    = threadIdx.x;
    const int lane = t & 63;
    const int wv   = t >> 6;
    const int wr   = wv >> 1;          // 0..3  (80-row group)
    const int wc   = wv & 1;           // 0..1  (128-col group)
    const int lr   = lane & 15;
    const int g4   = lane >> 4;        // 0..3 (k-granule)

    // A-panel-per-XCD pinning
    const int bm = blockIdx.x & 31;
    const int bn = blockIdx.x >> 5;    // 0..7
    const int m0 = bm * BM3, n0 = bn * BN3;

    // ---- per-thread staging map: 5 rounds x 16B (inverse-swizzled source) ----
    const unsigned short* gsrc[5];
    int ldsoff[5];
    {
        // rounds 0,1: A rows [L*128, L*128+128)
#pragma unroll
        for (int L = 0; L < 2; ++L) {
            int row = L * 128 + (t >> 2);
            int sg  = (t & 3) ^ ((row >> 1) & 3);
            gsrc[L] = simB + (size_t)(m0 + row) * KK + sg * 8;
            ldsoff[L] = L * 4096 + t * 8;
        }
        // round 2: waves 0-3 -> A rows 256-319 ; waves 4-7 -> B rows 0-63
        if (t < 256) {
            int row = 256 + (t >> 2);
            int sg  = (t & 3) ^ ((row >> 1) & 3);
            gsrc[2] = simB + (size_t)(m0 + row) * KK + sg * 8;
            ldsoff[2] = 8192 + t * 8;
        } else {
            int tt = t - 256;
            int row = tt >> 2;
            int sg  = (tt & 3) ^ ((row >> 1) & 3);
            gsrc[2] = W1T + (size_t)(n0 + row) * KK + sg * 8;
            ldsoff[2] = BBASE + tt * 8;
        }
        // round 3: B rows 64-191
        {
            int row = 64 + (t >> 2);
            int sg  = (t & 3) ^ ((row >> 1) & 3);
            gsrc[3] = W1T + (size_t)(n0 + row) * KK + sg * 8;
            ldsoff[3] = BBASE + 2048 + t * 8;
        }
        // round 4: B rows 192-255 (waves 4-7 duplicate waves 0-3: same data,
        // same dest -> benign; keeps per-wave load count uniform for vmcnt)
        {
            int tt = t & 255;
            int row = 192 + (tt >> 2);
            int sg  = (tt & 3) ^ ((row >> 1) & 3);
            gsrc[4] = W1T + (size_t)(n0 + row) * KK + sg * 8;
            ldsoff[4] = BBASE + 6144 + tt * 8;
        }
    }

    // swizzled ds_read offsets: (row>>1)&3 == (lr>>1)&3 for every fragment row
    const int gx   = (g4 ^ ((lr >> 1) & 3)) * 8;
    const int aoff = (wr * 80 + lr) * 32 + gx;
    const int boff = BBASE + (wc * 128 + lr) * 32 + gx;

    f32x4 acc[5][8];
#pragma unroll
    for (int m = 0; m < 5; ++m)
#pragma unroll
        for (int n = 0; n < 8; ++n)
            acc[m][n] = (f32x4){0.f, 0.f, 0.f, 0.f};

    // prologue: stage tiles 0,1,2 (15 loads/wave in flight)
    STAGE(0)
    STAGE(1)
    STAGE(2)

#pragma unroll 1
    for (int kt = 0; kt < NKT - 4; kt += 4) {
        BODY(kt,     "10", 1)
        BODY(kt + 1, "10", 1)
        BODY(kt + 2, "10", 1)
        BODY(kt + 3, "10", 1)
    }
    BODY(NKT - 4, "10", 1)   // stages tile NKT-1
    BODY(NKT - 3, "10", 0)
    BODY(NKT - 2, "5",  0)
    BODY(NKT - 1, "0",  0)

    // epilogue: relu(+b1), dot W2, 16-lane reduce, atomicAdd into s_pre
    float b1v[8], w2v[8];
#pragma unroll
    for (int n = 0; n < 8; ++n) {
        int col = n0 + wc * 128 + n * 16 + lr;
        b1v[n] = b1[col];
        w2v[n] = W2[col];
    }
#pragma unroll
    for (int m = 0; m < 5; ++m) {
#pragma unroll
        for (int r = 0; r < 4; ++r) {
            float rowsum = 0.f;
#pragma unroll
            for (int n = 0; n < 8; ++n) {
                float v = acc[m][n][r] + b1v[n];
                v = fmaxf(v, 0.f);
                rowsum = fmaf(v, w2v[n], rowsum);
            }
            rowsum += __shfl_xor(rowsum, 1);
            rowsum += __shfl_xor(rowsum, 2);
            rowsum += __shfl_xor(rowsum, 4);
            rowsum += __shfl_xor(rowsum, 8);
            if (lr == 0) {
                int row = m0 + wr * 80 + m * 16 + g4 * 4 + r;
                atomicAdd(&s_pre[row], rowsum);
            }
        }
    }
}

// ---------------------------------------------------------------------------
// Fallback GEMM (inline sim staging) — used only if ws too small for simB.
// ---------------------------------------------------------------------------
#define BM 128
#define BN 128
#define BK 32

__global__ __launch_bounds__(256) void gemm_kernel(
    const float* __restrict__ x0, const float* __restrict__ x1,
    const unsigned short* __restrict__ W1T,
    const float* __restrict__ b1, const float* __restrict__ W2,
    float* __restrict__ s_pre) {
    __shared__ unsigned short As[BM][BK];
    __shared__ unsigned short Bs[BN][BK];

    const int tid  = threadIdx.x;
    const int lane = tid & 63;
    const int wave = tid >> 6;
    const int wr = wave >> 1, wc = wave & 1;
    const int bm = blockIdx.x / (DD / BN);
    const int bn = blockIdx.x % (DD / BN);
    const int m0 = bm * BM, n0 = bn * BN;
    const int lr = lane & 15;
    const int lk = (lane >> 4) * 8;

    f32x4 acc[4][4];
#pragma unroll
    for (int m = 0; m < 4; ++m)
#pragma unroll
        for (int n = 0; n < 4; ++n)
            acc[m][n] = (f32x4){0.f, 0.f, 0.f, 0.f};

    for (int k0 = 0; k0 < KK; k0 += BK) {
        __syncthreads();
#pragma unroll
        for (int p = 0; p < 2; ++p) {
            int L  = tid + p * 256;
            int n  = L >> 2;
            int k8 = (L & 3) * 8;
            const unsigned short* g = &W1T[(size_t)(n0 + n) * KK + k0 + k8];
            unsigned short* l = &Bs[0][0] + (size_t)L * 8;
            __builtin_amdgcn_global_load_lds(
                (const __attribute__((address_space(1))) void*)g,
                (__attribute__((address_space(3))) void*)l, 16, 0, 0);
        }
        {
            const int f0 = k0 & (DD - 1);
            const bool second = (k0 >= DD);
            const int fc = (tid & 7) * 4;
            const float4 v0 = *(const float4*)&x0[f0 + fc];
#pragma unroll
            for (int p = 0; p < 4; ++p) {
                int row = p * 32 + (tid >> 3);
                const float4 v1 = *(const float4*)&x1[(size_t)(m0 + row) * DD + f0 + fc];
                ushort4 o;
                o.x = f2bf_rne(second ? (v0.x + v1.x) : fabsf(v0.x - v1.x));
                o.y = f2bf_rne(second ? (v0.y + v1.y) : fabsf(v0.y - v1.y));
                o.z = f2bf_rne(second ? (v0.z + v1.z) : fabsf(v0.z - v1.z));
                o.w = f2bf_rne(second ? (v0.w + v1.w) : fabsf(v0.w - v1.w));
                *(ushort4*)&As[row][fc] = o;
            }
        }
        __syncthreads();

        bf16x8 a[4], b[4];
#pragma unroll
        for (int m = 0; m < 4; ++m)
            a[m] = *(const bf16x8*)&As[wr * 64 + m * 16 + lr][lk];
#pragma unroll
        for (int n = 0; n < 4; ++n)
            b[n] = *(const bf16x8*)&Bs[wc * 64 + n * 16 + lr][lk];
#pragma unroll
        for (int m = 0; m < 4; ++m)
#pragma unroll
            for (int n = 0; n < 4; ++n)
                acc[m][n] = __builtin_amdgcn_mfma_f32_16x16x32_bf16(
                    a[m], b[n], acc[m][n], 0, 0, 0);
    }

    float b1v[4], w2v[4];
#pragma unroll
    for (int n = 0; n < 4; ++n) {
        int col = n0 + wc * 64 + n * 16 + lr;
        b1v[n] = b1[col];
        w2v[n] = W2[col];
    }
#pragma unroll
    for (int m = 0; m < 4; ++m) {
#pragma unroll
        for (int r = 0; r < 4; ++r) {
            float rowsum = 0.f;
#pragma unroll
            for (int n = 0; n < 4; ++n) {
                float v = acc[m][n][r] + b1v[n];
                v = fmaxf(v, 0.f);
                rowsum = fmaf(v, w2v[n], rowsum);
            }
            rowsum += __shfl_xor(rowsum, 1);
            rowsum += __shfl_xor(rowsum, 2);
            rowsum += __shfl_xor(rowsum, 4);
            rowsum += __shfl_xor(rowsum, 8);
            if (lr == 0) {
                int row = m0 + wr * 64 + m * 16 + (lane >> 4) * 4 + r;
                atomicAdd(&s_pre[row], rowsum);
            }
        }
    }
}

// ---------------------------------------------------------------------------
// Chunk-parallel BiLSTM. CHUNK=64, WARM=192; float4-batched s_pre loads.
// ---------------------------------------------------------------------------
#define CHUNK 64
#define WARM  192
#define NCH   (SS / CHUNK)   // 160

__device__ __forceinline__ float sigf(float x) {
    return 1.f / (1.f + __expf(-x));
}
__device__ __forceinline__ float tanhfast(float x) {
    return 2.f / (1.f + __expf(-2.f * x)) - 1.f;
}

__global__ __launch_bounds__(64) void lstm_kernel(
    const float* __restrict__ s_pre,
    const float* __restrict__ Wih_f, const float* __restrict__ Whh_f,
    const float* __restrict__ bih_f, const float* __restrict__ bhh_f,
    const float* __restrict__ Wih_b, const float* __restrict__ Whh_b,
    const float* __restrict__ bih_b, const float* __restrict__ bhh_b,
    float* __restrict__ hf, float* __restrict__ hb) {
    int id = blockIdx.x * blockDim.x + threadIdx.x;
    if (id >= 2 * NCH) return;
    int dir = id / NCH;
    int ch  = id % NCH;
    const float* Wih = dir ? Wih_b : Wih_f;
    const float* Whh = dir ? Whh_b : Whh_f;
    const float* bih = dir ? bih_b : bih_f;
    const float* bhh = dir ? bhh_b : bhh_f;
    const float wi0 = Wih[0], wi1 = Wih[1], wi2 = Wih[2], wi3 = Wih[3];
    const float wh0 = Whh[0], wh1 = Whh[1], wh2 = Whh[2], wh3 = Whh[3];
    const float bb0 = bih[0] + bhh[0], bb1 = bih[1] + bhh[1];
    const float bb2 = bih[2] + bhh[2], bb3 = bih[3] + bhh[3];

    const int pout0 = ch * CHUNK;
    int pstart = pout0 - WARM; if (pstart < 0) pstart = 0;
    const int pend = pout0 + CHUNK;

    float h = 0.f, c = 0.f;
    for (int p4 = pstart; p4 < pend; p4 += 4) {
        float4 xv;
        if (dir == 0) {
            xv = *(const float4*)&s_pre[p4];
        } else {
            const float4 tv = *(const float4*)&s_pre[SS - 4 - p4];
            xv = (float4){tv.w, tv.z, tv.y, tv.x};
        }
        const bool wr_out = (p4 >= pout0);
        const float xa[4] = {xv.x, xv.y, xv.z, xv.w};
#pragma unroll
        for (int q = 0; q < 4; ++q) {
            const int p = p4 + q;
            float x  = sigf(xa[q]);
            float g0 = fmaf(wi0, x, fmaf(wh0, h, bb0));
            float g1 = fmaf(wi1, x, fmaf(wh1, h, bb1));
            float g2 = fmaf(wi2, x, fmaf(wh2, h, bb2));
            float g3 = fmaf(wi3, x, fmaf(wh3, h, bb3));
            float gi = sigf(g0);
            float gf = sigf(g1);
            float gg = tanhfast(g2);
            float go = sigf(g3);
            c = fmaf(gf, c, gi * gg);
            h = go * tanhfast(c);
            if (wr_out) {
                int s = dir ? (SS - 1 - p) : p;
                if (dir) hb[s] = h; else hf[s] = h;
            }
        }
    }
}

// ---------------------------------------------------------------------------
// Head
// ---------------------------------------------------------------------------
__global__ __launch_bounds__(256) void final_kernel(
    const float* __restrict__ hf, const float* __restrict__ hb,
    const float* __restrict__ W3, const float* __restrict__ b3,
    float* __restrict__ out) {
    int j = blockIdx.x * blockDim.x + threadIdx.x;
    if (j >= (SS * 2) / 10) return;   // 2048
    float acc = b3[0];
#pragma unroll
    for (int i = 0; i < 5; ++i) {
        acc = fmaf(hf[5 * j + i], W3[2 * i],     acc);
        acc = fmaf(hb[5 * j + i], W3[2 * i + 1], acc);
    }
    out[j] = sigf(acc);
}

// ---------------------------------------------------------------------------
extern "C" void kernel_launch(void* const* d_in, const int* in_sizes, int n_in,
                              void* d_out, int out_size, void* d_ws, size_t ws_size,
                              hipStream_t stream) {
    const float* x0    = (const float*)d_in[0];
    const float* x1    = (const float*)d_in[1];
    const float* W1    = (const float*)d_in[2];
    const float* b1    = (const float*)d_in[3];
    const float* W2    = (const float*)d_in[4];
    const float* b2    = (const float*)d_in[5];
    const float* Wih_f = (const float*)d_in[6];
    const float* Whh_f = (const float*)d_in[7];
    const float* bih_f = (const float*)d_in[8];
    const float* bhh_f = (const float*)d_in[9];
    const float* Wih_b = (const float*)d_in[10];
    const float* Whh_b = (const float*)d_in[11];
    const float* bih_b = (const float*)d_in[12];
    const float* bhh_b = (const float*)d_in[13];
    const float* W3    = (const float*)d_in[14];
    const float* b3    = (const float*)d_in[15];
    float* out = (float*)d_out;

    char* ws = (char*)d_ws;
    const size_t w1t_bytes = (size_t)KK * DD * 2;        // 16 MB
    unsigned short* W1T = (unsigned short*)ws;
    float* s_pre = (float*)(ws + w1t_bytes);             // 40 KB
    float* hf    = s_pre + SS;
    float* hb    = hf + SS;
    size_t off_sim = w1t_bytes + 3 * (size_t)SS * 4;
    off_sim = (off_sim + 255) & ~(size_t)255;
    unsigned short* simB = (unsigned short*)(ws + off_sim);
    const size_t need = off_sim + (size_t)SS * KK * 2;   // ~100.8 MB

    if (ws_size >= need) {
        prep_sim_kernel<<<(KK / 64) * (DD / 64) + SS, 256, 0, stream>>>(
            W1, b2, x0, x1, W1T, s_pre, simB);
        gemm3_kernel<<<(SS / BM3) * (DD / BN3), 512, 0, stream>>>(
            simB, W1T, b1, W2, s_pre);
    } else {
        prep_sim_kernel<<<(KK / 64) * (DD / 64), 256, 0, stream>>>(
            W1, b2, x0, x1, W1T, s_pre, simB);
        gemm_kernel<<<(SS / BM) * (DD / BN), 256, 0, stream>>>(
            x0, x1, W1T, b1, W2, s_pre);
    }
    lstm_kernel<<<(2 * NCH + 63) / 64, 64, 0, stream>>>(
        s_pre, Wih_f, Whh_f, bih_f, bhh_f, Wih_b, Whh_b, bih_b, bhh_b, hf, hb);
    final_kernel<<<((SS * 2) / 10 + 255) / 256, 256, 0, stream>>>(hf, hb, W3, b3, out);
}